// Round 9
// baseline (249.502 us; speedup 1.0000x reference)
//
#include <hip/hip_runtime.h>

// incidence_matrix_learn on MI355X — round 9: symmetric-pair tiling.
// sim = nhat nhat^T is SYMMETRIC: tournament schedule mt=(tn+j)%T covers each
// unordered tile-pair once (scale0: 55/100 tiles, scale1: 21/36). Off-diagonal
// tiles accumulate row-side (registers) AND col-side (shfl col-reduce +
// global atomicAdd into per-(b,row) seG/posG); reduce_kernel finishes
// 10+log(se)-pos/c. Also __launch_bounds__(128,1): round-8's (128,2) made the
// compiler cap at 128 VGPR and spill A-frags (WRITE_SIZE 2 MB scratch).
// Validated algebra (rounds 1-8, absmax 0.0): top-k no-op; P via labels;
// fixed-shift-10 LSE; bf16 nhat; cnt = label-histogram - 1.

#define DDIM 512
#define BATCH 64

typedef __attribute__((ext_vector_type(8))) short short8;
typedef __attribute__((ext_vector_type(4))) float f32x4;

__device__ __forceinline__ unsigned short f2bf(float f) {
  unsigned int u = __float_as_uint(f);
  u += 0x7fffu + ((u >> 16) & 1u);   // RNE
  return (unsigned short)(u >> 16);
}

__device__ __forceinline__ void async16(const void* g, void* l) {
  __builtin_amdgcn_global_load_lds(
      (const __attribute__((address_space(1))) unsigned int*)g,
      (__attribute__((address_space(3))) unsigned int*)l, 16, 0, 0);
}

// Fused prep kernel, 256 threads. Blocks [0,1024): adj (both scales).
// Blocks [1024, 1024+16384): normalize, one WAVE per node row.
__global__ __launch_bounds__(256) void prep_kernel(
    const float* __restrict__ enod0, const float* __restrict__ ehy0,
    const float* __restrict__ enod1, const float* __restrict__ ehy1,
    float* __restrict__ adj0, float* __restrict__ adj1,
    int* __restrict__ labels0, int* __restrict__ labels1,
    const float* __restrict__ x0, const float* __restrict__ w0,
    const float* __restrict__ x1, const float* __restrict__ w1,
    unsigned short* __restrict__ nhat0, unsigned short* __restrict__ nhat1) {
  const int t = threadIdx.x;
  if (blockIdx.x < 1024) {
    // ---- adj path ----
    const bool s0 = blockIdx.x < 640;
    const int n = s0 ? blockIdx.x : blockIdx.x - 640;
    const int H = s0 ? 128 : 64;
    const float* enod = s0 ? enod0 : enod1;
    const float* ehy = s0 ? ehy0 : ehy1;
    float* out_adj = s0 ? adj0 : adj1;
    int* labels = s0 ? labels0 : labels1;
    __shared__ float erow[DDIM];
    __shared__ float red[128];
    __shared__ int lab;
    if (t < 128) ((float4*)erow)[t] = ((const float4*)(enod + (size_t)n * DDIM))[t];
    if (t == 0) lab = -1;
    __syncthreads();
    float v = 0.f;
    if (t < H) {
      const float4* hr = (const float4*)(ehy + (size_t)t * DDIM);
      float a = 0.f;
      #pragma unroll 8
      for (int d = 0; d < DDIM / 4; ++d) {
        float4 h = hr[d];
        float4 e = ((const float4*)erow)[d];
        a = fmaf(h.x, e.x, a); a = fmaf(h.y, e.y, a);
        a = fmaf(h.z, e.z, a); a = fmaf(h.w, e.w, a);
      }
      v = fmaxf(0.f, 3.0f * a);
    }
    if (t < 128) red[t] = v;
    __syncthreads();
    for (int s = 64; s > 0; s >>= 1) {
      if (t < s) red[t] = fmaxf(red[t], red[t + s]);
      __syncthreads();
    }
    const float mx = red[0];
    __syncthreads();
    const float e = (t < H) ? __expf(v - mx) : 0.f;
    if (t < 128) red[t] = e;
    __syncthreads();
    for (int s = 64; s > 0; s >>= 1) {
      if (t < s) red[t] += red[t + s];
      __syncthreads();
    }
    const float sum = red[0];
    if (t < H) {
      const float adj = e / sum;
      const float bin = (adj > 0.5f) ? 1.0f : 0.0f;
      out_adj[(size_t)n * H + t] = bin;
      if (bin > 0.f) lab = t;
    }
    __syncthreads();
    if (t == 0) labels[n] = lab;
  } else {
    // ---- normalize path: wave per row ----
    const int wave = t >> 6;
    const int lane = t & 63;
    const int g = (blockIdx.x - 1024) * 4 + wave;   // global row id, < 65536
    const bool s0 = g < BATCH * 640;
    const int gg = s0 ? g : g - BATCH * 640;
    const int N = s0 ? 640 : 384;
    const int L = s0 ? 512 : 256;
    const float* x = s0 ? x0 : x1;
    const float* w = s0 ? w0 : w1;
    unsigned short* nhat = s0 ? nhat0 : nhat1;
    const int b = gg / N;
    const int n = gg - b * N;
    const float* src = (n < L) ? (x + ((size_t)b * L + n) * DDIM)
                               : (w + (size_t)(n - L) * DDIM);
    const float4* rowp = (const float4*)src;
    const float4 v0 = rowp[lane];
    const float4 v1 = rowp[lane + 64];
    float ss = v0.x * v0.x + v0.y * v0.y + v0.z * v0.z + v0.w * v0.w +
               v1.x * v1.x + v1.y * v1.y + v1.z * v1.z + v1.w * v1.w;
    #pragma unroll
    for (int off = 32; off > 0; off >>= 1) ss += __shfl_xor(ss, off);
    const float rinv = 1.0f / fmaxf(sqrtf(ss), 1e-12f);
    ushort4 o0, o1;
    o0.x = f2bf(v0.x * rinv); o0.y = f2bf(v0.y * rinv);
    o0.z = f2bf(v0.z * rinv); o0.w = f2bf(v0.w * rinv);
    o1.x = f2bf(v1.x * rinv); o1.y = f2bf(v1.y * rinv);
    o1.z = f2bf(v1.z * rinv); o1.w = f2bf(v1.w * rinv);
    ushort4* op = (ushort4*)(nhat + ((size_t)b * N + n) * DDIM);
    op[lane] = o0;
    op[lane + 64] = o1;
  }
}

// 2 blocks. cnt[i] = hist[lab[i]] - 1 via 128-bin LDS label histogram.
__global__ __launch_bounds__(256) void cnt_kernel(
    const int* __restrict__ labels0, int* __restrict__ cnt0,
    const int* __restrict__ labels1, int* __restrict__ cnt1,
    int* __restrict__ valid) {
  const bool s0 = blockIdx.x == 0;
  const int* labels = s0 ? labels0 : labels1;
  int* cnt = s0 ? cnt0 : cnt1;
  int* validcnt = s0 ? valid : valid + 1;
  const int N = s0 ? 640 : 384;
  __shared__ int lab[640];
  __shared__ int hist[128];
  __shared__ int vc;
  const int t = threadIdx.x;
  if (t == 0) vc = 0;
  if (t < 128) hist[t] = 0;
  for (int i = t; i < N; i += 256) lab[i] = labels[i];
  __syncthreads();
  for (int i = t; i < N; i += 256)
    if (lab[i] >= 0) atomicAdd(&hist[lab[i]], 1);
  __syncthreads();
  int lv = 0;
  for (int i = t; i < N; i += 256) {
    const int c = (lab[i] >= 0) ? hist[lab[i]] - 1 : 0;
    cnt[i] = c;
    if (c > 0) ++lv;
  }
  if (lv > 0) atomicAdd(&vc, lv);
  __syncthreads();
  if (t == 0) *validcnt = vc;
}

// Symmetric-pair MFMA lse kernel: 128 threads (2 waves) per (b, tn).
// Tournament schedule: tiles mt=(tn+j)%T, j=0..ntj-1; every unordered tile
// pair once. Row-side accumulated in registers; col-side (j>0) shfl-reduced
// over rows and atomicAdd'ed into seG/posG[b*N + m]. Row-side flushed to the
// same arrays at block end. Wave holds 32 A-rows (two 16-row frag sets, full
// K=512); B double-buffered frag-order LDS chunks, prefetch 1 ahead.
__global__ __launch_bounds__(128, 1) void lse_kernel(
    const unsigned short* __restrict__ nhat0, const int* __restrict__ labels0,
    const unsigned short* __restrict__ nhat1, const int* __restrict__ labels1,
    float* __restrict__ seG0, float* __restrict__ posG0,
    float* __restrict__ seG1, float* __restrict__ posG1) {
  __shared__ short8 Bbuf[2][1024];   // 2 x 16 KB, frag-order
  __shared__ int labS[640];
  const int tid = threadIdx.x;
  const bool s0 = blockIdx.x < 640;
  const int i = s0 ? blockIdx.x : blockIdx.x - 640;
  const int N = s0 ? 640 : 384;
  const int T = s0 ? 10 : 6;
  const unsigned short* nhat = s0 ? nhat0 : nhat1;
  const int* labels = s0 ? labels0 : labels1;
  float* seG = s0 ? seG0 : seG1;
  float* posG = s0 ? posG0 : posG1;
  const int b = i & 63;        // XCD swizzle: batch fixes XCD residue
  const int tn = i >> 6;
  const int n0 = tn * 64;
  // tournament tile count: T=10: tn<5 -> 6 else 5; T=6: tn<3 -> 4 else 3
  const int ntj = s0 ? ((tn < 5) ? 6 : 5) : ((tn < 3) ? 4 : 3);
  const int wave = tid >> 6;   // 0..1
  const int lane = tid & 63;
  const int lrow = lane & 15;   // A-row within 16 / B-col / C-col
  const int lq = lane >> 4;     // k-chunk selector / C row group
  for (int t = tid; t < N; t += 128) labS[t] = labels[t];

  const size_t base = (size_t)b * N * DDIM;
  const int rw0 = n0 + wave * 32;   // wave owns rows rw0 .. rw0+31
  const unsigned short* Ap0 = nhat + base + (size_t)(rw0 + lrow) * DDIM + lq * 8;
  const unsigned short* Ap1 = nhat + base + (size_t)(rw0 + 16 + lrow) * DDIM + lq * 8;
  short8 a0[16], a1[16];
  #pragma unroll
  for (int ks = 0; ks < 16; ++ks) {
    a0[ks] = *(const short8*)(Ap0 + ks * 32);
    a1[ks] = *(const short8*)(Ap1 + ks * 32);
  }

  // stage chunk 0 (jt=0 -> mt=tn, kc=0): this wave's 8 frags
  const int f0 = wave * 8;
  #pragma unroll
  for (int fi = 0; fi < 8; ++fi) {
    const int f = f0 + fi;
    const int j = f >> 2, ks = f & 3;
    const unsigned short* g = nhat + base +
        (size_t)(n0 + j * 16 + lrow) * DDIM + ks * 32 + lq * 8;
    async16(g, &Bbuf[0][f * 64]);
  }
  __syncthreads();   // drains staging (vmcnt) + labS writes

  int labn[2][4];
  #pragma unroll
  for (int s = 0; s < 2; ++s)
    #pragma unroll
    for (int r = 0; r < 4; ++r) labn[s][r] = labS[rw0 + s * 16 + lq * 4 + r];

  float se[2][4] = {{0.f, 0.f, 0.f, 0.f}, {0.f, 0.f, 0.f, 0.f}};
  float pos[2][4] = {{0.f, 0.f, 0.f, 0.f}, {0.f, 0.f, 0.f, 0.f}};
  const int nchunks = ntj * 4;

  for (int jt = 0; jt < ntj; ++jt) {
    int mt = tn + jt; if (mt >= T) mt -= T;
    const int m0 = mt * 64;
    f32x4 acc[4][2];
    #pragma unroll
    for (int j = 0; j < 4; ++j) {
      acc[j][0] = (f32x4){0.f, 0.f, 0.f, 0.f};
      acc[j][1] = (f32x4){0.f, 0.f, 0.f, 0.f};
    }
    #pragma unroll
    for (int kc = 0; kc < 4; ++kc) {
      // prefetch chunk (jt*4 + kc + 1) into buffer parity (kc+1)&1
      const int nc = jt * 4 + kc + 1;
      if (nc < nchunks) {
        const int jt2 = nc >> 2, kc2 = nc & 3;
        int mt2 = tn + jt2; if (mt2 >= T) mt2 -= T;
        short8* dst = &Bbuf[(kc + 1) & 1][0];
        #pragma unroll
        for (int fi = 0; fi < 8; ++fi) {
          const int f = f0 + fi;
          const int j = f >> 2, ks = f & 3;
          const unsigned short* g = nhat + base +
              (size_t)(mt2 * 64 + j * 16 + lrow) * DDIM +
              kc2 * 128 + ks * 32 + lq * 8;
          async16(g, dst + f * 64);
        }
      }
      // compute chunk kc from Bbuf[kc&1]; all register indices compile-time
      const short8* bb = &Bbuf[kc & 1][0];
      #pragma unroll
      for (int ks = 0; ks < 4; ++ks) {
        const short8 b0 = bb[(0 + ks) * 64 + lane];
        const short8 b1 = bb[(4 + ks) * 64 + lane];
        const short8 b2 = bb[(8 + ks) * 64 + lane];
        const short8 b3 = bb[(12 + ks) * 64 + lane];
        const short8 av0 = a0[kc * 4 + ks];
        const short8 av1 = a1[kc * 4 + ks];
        acc[0][0] = __builtin_amdgcn_mfma_f32_16x16x32_bf16(av0, b0, acc[0][0], 0, 0, 0);
        acc[0][1] = __builtin_amdgcn_mfma_f32_16x16x32_bf16(av1, b0, acc[0][1], 0, 0, 0);
        acc[1][0] = __builtin_amdgcn_mfma_f32_16x16x32_bf16(av0, b1, acc[1][0], 0, 0, 0);
        acc[1][1] = __builtin_amdgcn_mfma_f32_16x16x32_bf16(av1, b1, acc[1][1], 0, 0, 0);
        acc[2][0] = __builtin_amdgcn_mfma_f32_16x16x32_bf16(av0, b2, acc[2][0], 0, 0, 0);
        acc[2][1] = __builtin_amdgcn_mfma_f32_16x16x32_bf16(av1, b2, acc[2][1], 0, 0, 0);
        acc[3][0] = __builtin_amdgcn_mfma_f32_16x16x32_bf16(av0, b3, acc[3][0], 0, 0, 0);
        acc[3][1] = __builtin_amdgcn_mfma_f32_16x16x32_bf16(av1, b3, acc[3][1], 0, 0, 0);
      }
      __syncthreads();   // staging for nc drained; buffer swap safe
    }
    // epilogue: row-side always; col-side partials per j
    float colE[4] = {0.f, 0.f, 0.f, 0.f};
    float colP[4] = {0.f, 0.f, 0.f, 0.f};
    #pragma unroll
    for (int j = 0; j < 4; ++j) {
      const int m = m0 + j * 16 + lrow;
      const int labm = labS[m];
      #pragma unroll
      for (int s = 0; s < 2; ++s) {
        const int row0 = rw0 + s * 16 + lq * 4;
        #pragma unroll
        for (int r = 0; r < 4; ++r) {
          const float sim = acc[j][s][r] * 10.0f;    // 1/TAU
          const float e = __expf(sim - 10.0f);       // fixed shift (diag max)
          const bool match =
              labn[s][r] >= 0 && labm == labn[s][r] && m != row0 + r;
          const float p = match ? sim : 0.f;
          se[s][r] += e;
          pos[s][r] += p;
          colE[j] += e;
          colP[j] += p;
        }
      }
    }
    if (jt > 0) {   // col-side: symmetric contribution to rows m (off-diag only)
      #pragma unroll
      for (int j = 0; j < 4; ++j) {
        float ce = colE[j], cp = colP[j];
        ce += __shfl_xor(ce, 16); ce += __shfl_xor(ce, 32);
        cp += __shfl_xor(cp, 16); cp += __shfl_xor(cp, 32);
        if (lq == 0) {
          const int m = m0 + j * 16 + lrow;
          atomicAdd(&seG[b * N + m], ce);
          atomicAdd(&posG[b * N + m], cp);
        }
      }
    }
  }

  // row-side flush: reduce across the 16 col-lanes of each row group
  #pragma unroll
  for (int off = 1; off <= 8; off <<= 1) {
    #pragma unroll
    for (int s = 0; s < 2; ++s)
      #pragma unroll
      for (int r = 0; r < 4; ++r) {
        se[s][r] += __shfl_xor(se[s][r], off);
        pos[s][r] += __shfl_xor(pos[s][r], off);
      }
  }
  if (lrow == 0) {
    #pragma unroll
    for (int s = 0; s < 2; ++s)
      #pragma unroll
      for (int r = 0; r < 4; ++r) {
        const int row = rw0 + s * 16 + lq * 4 + r;
        atomicAdd(&seG[b * N + row], se[s][r]);
        atomicAdd(&posG[b * N + row], pos[s][r]);
      }
  }
}

// 256 blocks x 256 thr over 65536 rows: loss_i = 10+log(se)-pos/c, wave-reduce,
// atomicAdd per wave into acc[scale]. Wave never straddles scales (40960%64==0).
__global__ __launch_bounds__(256) void reduce_kernel(
    const float* __restrict__ seG0, const float* __restrict__ posG0,
    const int* __restrict__ cnt0, const float* __restrict__ seG1,
    const float* __restrict__ posG1, const int* __restrict__ cnt1,
    float* __restrict__ acc) {
  const int idx = blockIdx.x * 256 + threadIdx.x;
  float v = 0.f;
  int sel;
  if (idx < BATCH * 640) {
    sel = 0;
    const int n = idx % 640;
    const int c = cnt0[n];
    if (c > 0) v = (10.0f + logf(seG0[idx])) - posG0[idx] / (float)c;
  } else {
    sel = 1;
    const int k = idx - BATCH * 640;
    const int n = k % 384;
    const int c = cnt1[n];
    if (c > 0) v = (10.0f + logf(seG1[k])) - posG1[k] / (float)c;
  }
  #pragma unroll
  for (int off = 32; off > 0; off >>= 1) v += __shfl_xor(v, off);
  if ((threadIdx.x & 63) == 0) atomicAdd(&acc[sel], v);
}

__global__ void final_kernel(const float* __restrict__ acc,
                             const int* __restrict__ valid,
                             float* __restrict__ out) {
  float l = 0.f;
  if (valid[0] > 0) l += acc[0] / (float)(BATCH * valid[0]);
  if (valid[1] > 0) l += acc[1] / (float)(BATCH * valid[1]);
  out[0] = l;
}

extern "C" void kernel_launch(void* const* d_in, const int* in_sizes, int n_in,
                              void* d_out, int out_size, void* d_ws,
                              size_t ws_size, hipStream_t stream) {
  const float* x0 = (const float*)d_in[0];
  const float* x1 = (const float*)d_in[1];
  const float* w0 = (const float*)d_in[2];
  const float* w1 = (const float*)d_in[3];
  const float* ehy0 = (const float*)d_in[4];
  const float* ehy1 = (const float*)d_in[5];
  const float* enod0 = (const float*)d_in[6];
  const float* enod1 = (const float*)d_in[7];

  float* out = (float*)d_out;
  float* adj0 = out;                       // 640*128
  float* adj1 = out + 640 * 128;           // 384*64
  float* lossp = out + 640 * 128 + 384 * 64;

  unsigned short* nhat0 = (unsigned short*)d_ws;
  unsigned short* nhat1 = nhat0 + (size_t)BATCH * 640 * DDIM;
  int* ip = (int*)(nhat1 + (size_t)BATCH * 384 * DDIM);
  int* labels0 = ip;
  int* labels1 = labels0 + 640;
  int* cnt0 = labels1 + 384;
  int* cnt1 = cnt0 + 640;
  int* valid = cnt1 + 384;
  float* fz = (float*)(valid + 2);         // zeroed region start
  float* seG0 = fz;                        // 64*640
  float* posG0 = seG0 + BATCH * 640;
  float* seG1 = posG0 + BATCH * 640;       // 64*384
  float* posG1 = seG1 + BATCH * 384;
  float* acc = posG1 + BATCH * 384;        // 2

  hipMemsetAsync(fz, 0,
                 (size_t)(2 * BATCH * (640 + 384) + 2) * sizeof(float), stream);
  prep_kernel<<<1024 + 16384, 256, 0, stream>>>(
      enod0, ehy0, enod1, ehy1, adj0, adj1, labels0, labels1,
      x0, w0, x1, w1, nhat0, nhat1);
  cnt_kernel<<<2, 256, 0, stream>>>(labels0, cnt0, labels1, cnt1, valid);
  lse_kernel<<<1024, 128, 0, stream>>>(nhat0, labels0, nhat1, labels1,
                                       seG0, posG0, seG1, posG1);
  reduce_kernel<<<256, 256, 0, stream>>>(seG0, posG0, cnt0, seG1, posG1, cnt1,
                                         acc);
  final_kernel<<<1, 1, 0, stream>>>(acc, valid, lossp);
}